// Round 1
// baseline (259.191 us; speedup 1.0000x reference)
//
#include <hip/hip_runtime.h>
#include <math.h>

#define BB 128   // batch
#define NN 96    // perturbations
#define DD 3072  // C*H*W
#define KK 10    // classes
#define G  4     // n's per block in k1

// ---------------- Kernel 1: logits + per-(n,b) losses ----------------
// grid = 3072 blocks = (B=128) * (96/G=24 n-groups), block = 256 threads.
// Thread t owns i = c*1024 + 4t .. +3 per chunk c (3 chunks), keeps the
// 4x10 W slice in registers, loops the 4 n's of its group.
__global__ __launch_bounds__(256) void k1_logits(
    const float* __restrict__ imgs,    // (128, 3072)
    const float* __restrict__ deltas,  // (96, 128, 3072)
    const float* __restrict__ W,       // (3072, 10)
    const float* __restrict__ bias,    // (10)
    const int*   __restrict__ labels,  // (128)
    float* __restrict__ l1_ws,         // (128, 96)
    float* __restrict__ l2_ws)         // (128, 96)
{
    const int t   = threadIdx.x;
    const int bid = blockIdx.x;
    const int b   = bid & 127;
    const int n0  = (bid >> 7) * G;

    float acc[G][KK];
#pragma unroll
    for (int j = 0; j < G; ++j)
#pragma unroll
        for (int k = 0; k < KK; ++k) acc[j][k] = 0.f;

#pragma unroll
    for (int c = 0; c < 3; ++c) {
        const int i0 = c * 1024 + t * 4;
        // Load W rows i0..i0+3 (40 consecutive floats, 16B-aligned: 160*t)
        float w[40];
        const float4* wp = (const float4*)(W + (size_t)i0 * KK);
#pragma unroll
        for (int m = 0; m < 10; ++m) {
            float4 v = wp[m];
            w[4*m+0] = v.x; w[4*m+1] = v.y; w[4*m+2] = v.z; w[4*m+3] = v.w;
        }
        const float4 im = *(const float4*)(imgs + (size_t)b * DD + i0);
#pragma unroll
        for (int j = 0; j < G; ++j) {
            const int n = n0 + j;
            const float4 dl = *(const float4*)(deltas + ((size_t)(n * BB + b)) * DD + i0);
            const float x0 = fminf(fmaxf(im.x + dl.x, 0.f), 1.f);
            const float x1 = fminf(fmaxf(im.y + dl.y, 0.f), 1.f);
            const float x2 = fminf(fmaxf(im.z + dl.z, 0.f), 1.f);
            const float x3 = fminf(fmaxf(im.w + dl.w, 0.f), 1.f);
#pragma unroll
            for (int k = 0; k < KK; ++k) {
                // W[(i0+r)*10+k] == w[r*10+k]
                acc[j][k] = fmaf(x3, w[30+k],
                            fmaf(x2, w[20+k],
                            fmaf(x1, w[10+k],
                            fmaf(x0, w[k], acc[j][k]))));
            }
        }
    }

    // Block reduction: LDS transpose red[v][t], v = j*10+k  (40 KB)
    __shared__ float red[40 * 256];
#pragma unroll
    for (int j = 0; j < G; ++j)
#pragma unroll
        for (int k = 0; k < KK; ++k)
            red[(j * KK + k) * 256 + t] = acc[j][k];
    __syncthreads();

    const int wid  = t >> 6;   // wave id 0..3  -> handles n = n0 + wid
    const int lane = t & 63;
    float lg[KK];
#pragma unroll
    for (int k = 0; k < KK; ++k) {
        const float* row = red + (wid * KK + k) * 256;
        float s = row[lane] + row[lane + 64] + row[lane + 128] + row[lane + 192];
#pragma unroll
        for (int off = 32; off >= 1; off >>= 1)
            s += __shfl_down(s, off, 64);
        lg[k] = s;   // valid on lane 0
    }

    if (lane == 0) {
        const int n = n0 + wid;
#pragma unroll
        for (int k = 0; k < KK; ++k) lg[k] += bias[k];
        // top-1 (first max, matches top_k tie-break: lower index)
        int top1 = 0; float m1 = lg[0];
#pragma unroll
        for (int k = 1; k < KK; ++k) if (lg[k] > m1) { m1 = lg[k]; top1 = k; }
        // second (first max among k != top1)
        int sec = (top1 == 0) ? 1 : 0; float m2 = lg[sec];
#pragma unroll
        for (int k = 0; k < KK; ++k)
            if (k != top1 && lg[k] > m2) { m2 = lg[k]; sec = k; }
        // log-sum-exp (max-stabilized, like jax log_softmax)
        float se = 0.f;
#pragma unroll
        for (int k = 0; k < KK; ++k) se += expf(lg[k] - m1);
        const float lse = m1 + logf(se);
        const int lab = labels[b];
        const float loss1 = lse - lg[lab];
        const float loss2 = (top1 == lab) ? (lse - lg[sec]) : -10000.0f;
        l1_ws[b * NN + n] = loss1;
        l2_ws[b * NN + n] = loss2;
    }
}

// ---------------- Kernel 2: per-b stable rank-ind selection ----------------
// grid = 128 blocks (one per b), block = 128 threads (96 active).
__global__ __launch_bounds__(128) void k2_select(
    const float* __restrict__ l1_ws, const float* __restrict__ l2_ws,
    const int* __restrict__ ind_p, float* __restrict__ perb)
{
    const int b = blockIdx.x;
    const int t = threadIdx.x;
    __shared__ float sd[NN];
    __shared__ float sl2[NN];
    __shared__ float ssel;
    __shared__ float swsum[2];

    float myl1 = 0.f, myd = 0.f;
    if (t < NN) {
        const float a = l1_ws[b * NN + t];
        const float c = l2_ws[b * NN + t];
        myl1 = a; myd = a - c;
        sd[t] = myd; sl2[t] = c;
    }
    __syncthreads();

    if (t < NN) {
        int rank = 0;
        for (int j = 0; j < NN; ++j) {
            const float dj = sd[j];
            rank += (dj < myd) || (dj == myd && j < t);  // stable argsort semantics
        }
        if (rank == ind_p[0]) ssel = sl2[t];
    }

    float s = myl1;
#pragma unroll
    for (int off = 32; off >= 1; off >>= 1) s += __shfl_down(s, off, 64);
    if ((t & 63) == 0) swsum[t >> 6] = s;
    __syncthreads();
    if (t == 0) {
        const float total = swsum[0] + swsum[1];
        perb[b] = total / 96.0f - ssel;
    }
}

// ---------------- Kernel 3: final mean over b ----------------
__global__ __launch_bounds__(128) void k3_final(
    const float* __restrict__ perb, float* __restrict__ out)
{
    const int t = threadIdx.x;
    float s = perb[t];
#pragma unroll
    for (int off = 32; off >= 1; off >>= 1) s += __shfl_down(s, off, 64);
    __shared__ float sw[2];
    if ((t & 63) == 0) sw[t >> 6] = s;
    __syncthreads();
    if (t == 0) out[0] = (sw[0] + sw[1]) / 128.0f;
}

extern "C" void kernel_launch(void* const* d_in, const int* in_sizes, int n_in,
                              void* d_out, int out_size, void* d_ws, size_t ws_size,
                              hipStream_t stream) {
    const float* imgs   = (const float*)d_in[0];
    const float* deltas = (const float*)d_in[1];
    const float* W      = (const float*)d_in[2];
    const float* bias   = (const float*)d_in[3];
    const int*   labels = (const int*)d_in[4];
    const int*   ind    = (const int*)d_in[5];
    float* out = (float*)d_out;

    float* l1_ws = (float*)d_ws;             // 12288 floats
    float* l2_ws = l1_ws + NN * BB;          // 12288 floats
    float* perb  = l2_ws + NN * BB;          // 128 floats

    k1_logits<<<dim3(BB * (NN / G)), dim3(256), 0, stream>>>(
        imgs, deltas, W, bias, labels, l1_ws, l2_ws);
    k2_select<<<dim3(BB), dim3(128), 0, stream>>>(l1_ws, l2_ws, ind, perb);
    k3_final<<<dim3(1), dim3(128), 0, stream>>>(perb, out);
}